// Round 18
// baseline (169.970 us; speedup 1.0000x reference)
//
#include <hip/hip_runtime.h>
#include <hip/hip_bf16.h>
#include <math.h>

// ---------------------------------------------------------------------------
// Problem constants
// ---------------------------------------------------------------------------
constexpr int B = 8;
constexpr int N = 2048;
constexpr int KNN = 20;
constexpr int H = 128;
constexpr int P = 3 * N;  // 6144 pixels per batch
constexpr int QPW = 8;    // queries (waves) per knn_edge block

// ws layout (float offsets)
constexpr int OWT2   = 8448;      // W2/D2 second-half TRANSPOSED [c<128][m<256] (32768)
constexpr int OWT3   = 41216;     // W3/D3 second-half transposed (32768)
constexpr int OPS1   = 73984;     // poolsum1 shadows [8][B][128][3] = 24576
constexpr int OPS2   = 98560;     // poolsum2 shadows = 24576
constexpr int OOUTS  = 123136;    // out shadows [8][B][384] = 24576
constexpr int OWB1   = 160000;    // Wbig1 bf16 hi/lo, FRAGMENT-MAJOR [ks][256][32h] (16384 f)
constexpr int OWB2   = 176384;    // Wbig2 fragment-major (32768 f)
constexpr int OWB3   = 209152;    // Wbig3 fragment-major (32768 f)
constexpr int OXP0   = 569600;    // Xp0 bf16 [b][P][128] (3145728 f-equiv)
constexpr int OXP2   = 569600;    // Xp2 bf16 [b][P][256] reuses Xp0 region
constexpr int OXP1   = 6861056;   // Xp1 bf16 [b][P][256] (6291456 f-equiv)
// max extent 13,152,512 floats ~= 52.6 MB

constexpr int ZERO_BASE = OPS1;   // zeroed region = ps1+ps2+outs
constexpr int ZERO_CNT  = 73728;

typedef __attribute__((ext_vector_type(8))) short bf16x8;
typedef __attribute__((ext_vector_type(4))) float f32x4;

__device__ __forceinline__ unsigned short f2bf(float x) {
  __hip_bfloat16 h = __float2bfloat16(x);
  return *(unsigned short*)&h;
}
__device__ __forceinline__ float bf2f(unsigned short u) {
  __hip_bfloat16 h;
  *(unsigned short*)&h = u;
  return __bfloat162float(h);
}
// pack x as (hi, lo) bf16 pair in one uint (hi at lower address)
__device__ __forceinline__ unsigned int packhl(float x) {
  unsigned short hi = f2bf(x);
  float lo = x - bf2f(hi);
  unsigned short ls = f2bf(lo);
  return (unsigned)hi | ((unsigned)ls << 16);
}

// ---------------------------------------------------------------------------
// Wave-wide bitonic sort of 64 u64 keys, descending (larger key = better).
// Key = ord(value)<<32 | ~index  ==>  value desc, ties -> smaller index.
// ---------------------------------------------------------------------------
__device__ __forceinline__ void wave_sort_key(unsigned long long& k, int lane) {
#pragma unroll
  for (int kk = 2; kk <= 64; kk <<= 1) {
#pragma unroll
    for (int j = kk >> 1; j > 0; j >>= 1) {
      unsigned long long pk =
          (unsigned long long)__shfl_xor((long long)k, j);
      bool iam_lower   = (lane & j) == 0;
      bool dir_desc    = (lane & kk) == 0;
      bool p_better    = pk > k;
      bool want_better = (dir_desc == iam_lower);
      k = (p_better == want_better) ? pk : k;
    }
  }
}

// ---------------------------------------------------------------------------
// K2 (FUSED): prep + exact top-20 KNN + edge + pos layer + mean-k -> Xp0.
// (unchanged from round 17)
// ---------------------------------------------------------------------------
__global__ __launch_bounds__(512, 8) void knn_edge_kernel(
    const float* __restrict__ pc, const float* __restrict__ Wpos,
    const float* __restrict__ Dp,
    const float* __restrict__ W1, const float* __restrict__ D1,
    const float* __restrict__ W2, const float* __restrict__ D2,
    const float* __restrict__ W3, const float* __restrict__ D3,
    float* __restrict__ ws) {
  __shared__ float4 spt[N];                       // 32 KB (2x,2y,2z,xx)
  __shared__ __align__(16) unsigned char sphase[QPW][640];   // 5 KB
  int tid = threadIdx.x;
  int b = blockIdx.y;
  int bid = blockIdx.y * gridDim.x + blockIdx.x;  // 0..2047
  int wv = tid >> 6, lane = tid & 63;
  unsigned short* Xp0 = (unsigned short*)(ws + OXP0);
  unsigned short* sbufw = (unsigned short*)sphase[wv];
  float4* erw = (float4*)sphase[wv];

  // hoisted edge-phase weight loads (latency hidden under distance pass)
  int o = lane;
  float w0 = Wpos[o * 3 + 0], w1 = Wpos[o * 3 + 1], w2 = Wpos[o * 3 + 2];
  float e0 = Dp[o * 3 + 0], e1 = Dp[o * 3 + 1], e2 = Dp[o * 3 + 2];

  // ---- folded prep: distributed shadow zeroing (1 store/thread) ----------
  {
    int zi = bid * 512 + tid;
    if (zi < ZERO_CNT) ws[ZERO_BASE + zi] = 0.f;
  }
  // ---- folded prep: 768 weight rows over blocks 0..95 (one wave/row) -----
  if (bid < 96) {
    int rr = bid * 8 + wv;  // 0..767
    const float* src;
    float* tdst = nullptr;
    unsigned int* pdst;   // base of fragment-major region + m*16
    int C, Cpack;
    bool norm;
    if (rr < 128)      { src = W1 + rr * 64;            C = 64;  Cpack = 64;  norm = true;
                         pdst = (unsigned int*)(ws + OWB1) + rr * 16; }
    else if (rr < 256) { int m = rr - 128; src = D1 + m * 64;  C = 64;  Cpack = 64;  norm = false;
                         pdst = (unsigned int*)(ws + OWB1) + (m + 128) * 16; }
    else if (rr < 384) { int m = rr - 256; src = W2 + m * 256; C = 256; Cpack = 128; norm = true;
                         pdst = (unsigned int*)(ws + OWB2) + m * 16; tdst = ws + OWT2 + m; }
    else if (rr < 512) { int m = rr - 384; src = D2 + m * 256; C = 256; Cpack = 128; norm = false;
                         pdst = (unsigned int*)(ws + OWB2) + (m + 128) * 16; tdst = ws + OWT2 + 128 + m; }
    else if (rr < 640) { int m = rr - 512; src = W3 + m * 256; C = 256; Cpack = 128; norm = true;
                         pdst = (unsigned int*)(ws + OWB3) + m * 16; tdst = ws + OWT3 + m; }
    else               { int m = rr - 640; src = D3 + m * 256; C = 256; Cpack = 128; norm = false;
                         pdst = (unsigned int*)(ws + OWB3) + (m + 128) * 16; tdst = ws + OWT3 + 128 + m; }
    float s = 1.f;
    if (norm) {
      float a = 0.f;
      for (int i = lane; i < C; i += 64) a += src[i];
#pragma unroll
      for (int off = 32; off > 0; off >>= 1) a += __shfl_xor(a, off);
      s = a;
    }
    for (int i = lane; i < C; i += 64) {
      float val = src[i] / s;  // exact when s==1
      if (i < Cpack) pdst[(i >> 4) * 4096 + (i & 15)] = packhl(val);
      if (tdst && i >= 128) tdst[(i - 128) * 256] = val;
    }
  }

  // ---- stage point cloud ---------------------------------------------------
  const float* pcb = pc + (size_t)b * N * 3;
  for (int i = tid; i < N; i += 512) {
    float x = pcb[i * 3 + 0], y = pcb[i * 3 + 1], z = pcb[i * 3 + 2];
    float xx = __fadd_rn(__fadd_rn(__fmul_rn(x, x), __fmul_rn(y, y)), __fmul_rn(z, z));
    spt[i] = make_float4(2.f * x, 2.f * y, 2.f * z, xx);
  }
  __syncthreads();
  int q = blockIdx.x * QPW + wv;
  float4 qp = spt[q];
  float qx = 0.5f * qp.x, qy = 0.5f * qp.y, qz = 0.5f * qp.z, qxx = qp.w;

  float dv[32];
  float lmax = -INFINITY;
#pragma unroll
  for (int i = 0; i < 32; ++i) {
    float4 m = spt[i * 64 + lane];
    float A = __fadd_rn(__fadd_rn(__fmul_rn(m.x, qx), __fmul_rn(m.y, qy)),
                        __fmul_rn(m.z, qz));
    float d = __fsub_rn(__fsub_rn(A, qxx), m.w);
    dv[i] = d;
    lmax = fmaxf(lmax, d);
  }

  // value-only bitonic sort (descending) of the 64 lane-maxes; take #19
  float sv = lmax;
#pragma unroll
  for (int k = 2; k <= 64; k <<= 1) {
#pragma unroll
    for (int j = k >> 1; j > 0; j >>= 1) {
      float pv = __shfl_xor(sv, j);
      bool keep_max = ((lane & k) == 0) == ((lane & j) == 0);
      sv = keep_max ? fmaxf(sv, pv) : fminf(sv, pv);
    }
  }
  float tval = __shfl(sv, 19);  // 20th-largest lane-max <= V20 (provable)

  // registerized compact: per-lane survivor mask + shfl prefix scan
  unsigned msk = 0u;
#pragma unroll
  for (int i = 0; i < 32; ++i) msk |= (dv[i] >= tval) ? (1u << i) : 0u;
  int cnt = __popc(msk);
  int scan = cnt;
#pragma unroll
  for (int off = 1; off < 64; off <<= 1) {
    int t = __shfl_up(scan, off);
    scan += (lane >= off) ? t : 0;
  }
  int S = __shfl(scan, 63);
  int pos = scan - cnt;  // exclusive prefix
  unsigned mm = msk;
  while (mm) {
    int i = __ffs(mm) - 1;
    mm &= mm - 1;
    if (pos < 192) sbufw[pos] = (unsigned short)(i * 64 + lane);
    ++pos;
  }

  auto distOf = [&](int m) -> float {
    float4 mp = spt[m];
    float A = __fadd_rn(__fadd_rn(__fmul_rn(mp.x, qx), __fmul_rn(mp.y, qy)),
                        __fmul_rn(mp.z, qz));
    return __fsub_rn(__fsub_rn(A, qxx), mp.w);
  };
  auto mkkey = [&](int m) -> unsigned long long {
    float d = distOf(m);
    unsigned u = __float_as_uint(d);
    u ^= (u >> 31) ? 0xFFFFFFFFu : 0x80000000u;
    return ((unsigned long long)u << 32) | (unsigned)(~m);
  };

  unsigned long long key = 0ULL;  // padding key: below every real key
  if (S <= 64) {
    if (lane < S) key = mkkey(sbufw[lane]);
    wave_sort_key(key, lane);
  } else if (S <= 192) {
    int p2 = 0;
    while (p2 < S) {
      if (lane >= KNN) {
        int t = p2 + lane - KNN;
        key = (t < S) ? mkkey(sbufw[t]) : 0ULL;
      }
      wave_sort_key(key, lane);
      p2 += 64 - KNN;
    }
  } else {
    int p2 = 0;
    while (p2 < N) {
      if (lane >= KNN) {
        int t = p2 + lane - KNN;
        key = (t < N) ? mkkey(t) : 0ULL;
      }
      wave_sort_key(key, lane);
      p2 += 64 - KNN;
    }
  }
  int cm = ~((unsigned)key);  // valid in lanes 0..19

  // ---- edge geometry precompute: lane k<20 computes e/r once --------------
  if (lane < KNN) {
    float4 t = spt[cm];
    float nx = 0.5f * t.x, ny = 0.5f * t.y, nz = 0.5f * t.z;
    float ex = nx - qx, ey = ny - qy, ez = nz - qz;
    float rx = ny * qz - nz * qy;
    float ry = nz * qx - nx * qz;
    float rz = nx * qy - ny * qx;
    erw[2 * lane + 0] = make_float4(ex, ey, ez, 0.f);
    erw[2 * lane + 1] = make_float4(rx, ry, rz, 0.f);
  }

  // ---- edge + pos layer (lane o = channel o) -------------------------------
  {
    float s = (w0 + w2) + w1;
    w0 = w0 / s; w1 = w1 / s; w2 = w2 / s;
  }
  float cx = qx, cy = qy, cz = qz;  // exact raw coords (0.5 * 2x)
  float pcx = w1 * cx, pcy = w1 * cy, pcz = w1 * cz;
  float dcx = e1 * cx, dcy = e1 * cy, dcz = e1 * cz;
  float ax = 0.f, ay = 0.f, az = 0.f;
#pragma unroll 4
  for (int k = 0; k < KNN; ++k) {
    float4 e4 = erw[2 * k + 0];   // broadcast LDS reads
    float4 r4 = erw[2 * k + 1];
    float ex = e4.x, ey = e4.y, ez = e4.z;
    float rx = r4.x, ry = r4.y, rz = r4.z;
    float px = fmaf(w0, ex, fmaf(w2, rx, pcx));
    float py = fmaf(w0, ey, fmaf(w2, ry, pcy));
    float pz = fmaf(w0, ez, fmaf(w2, rz, pcz));
    float dx = fmaf(e0, ex, fmaf(e2, rx, dcx));
    float dy = fmaf(e0, ey, fmaf(e2, ry, dcy));
    float dz = fmaf(e0, ez, fmaf(e2, rz, dcz));
    float dot = fmaf(px, dx, fmaf(py, dy, pz * dz));
    float dns = fmaf(dx, dx, fmaf(dy, dy, dz * dz)) + 1e-6f;
    float r0 = __builtin_amdgcn_rcpf(dns);
    r0 = r0 * fmaf(-dns, r0, 2.0f);          // 1 Newton step
    float f = (dot < 0.f) ? dot * r0 : 0.f;
    ax = fmaf(-f, dx, px) + ax;
    ay = fmaf(-f, dy, py) + ay;
    az = fmaf(-f, dz, pz) + az;
  }
  int pbase = ((q >> 4) * 48) + (q & 15);
  unsigned short* dst = Xp0 + ((size_t)b * P + pbase) * 128 + 2 * o;
  *(unsigned int*)(dst)              = packhl(ax * (1.f / 20.f));
  *(unsigned int*)(dst + 16 * 128)   = packhl(ay * (1.f / 20.f));
  *(unsigned int*)(dst + 32 * 128)   = packhl(az * (1.f / 20.f));
}

// ---------------------------------------------------------------------------
// K9: merge 8 out shadows -> d_out (mean over N).
// ---------------------------------------------------------------------------
__global__ __launch_bounds__(256) void out_merge_kernel(
    const float* __restrict__ outs, float* __restrict__ out) {
  int idx = blockIdx.x * 256 + threadIdx.x;  // 3072
  if (idx >= B * 384) return;
  float s = 0.f;
#pragma unroll
  for (int k = 0; k < 8; ++k) s += outs[k * 3072 + idx];
  out[idx] = s * (1.f / 2048.f);
}

// ---------------------------------------------------------------------------
// K4/K6/K8: MFMA VNT layer.  Round-18 pipeline polish (all bit-identical):
//  - X staging: load-ALL-then-store-all (max outstanding global loads);
//  - K-loop: B fragments prefetched one ks ahead (bnxt) alongside anxt;
//  - epilogue: Xq pack-stores issued BEFORE pool atomics.
// ---------------------------------------------------------------------------
template <int K2, bool HASPOOL, bool LAST>
__global__ __launch_bounds__(256, 4) void gemm_vnt_kernel(
    const unsigned short* __restrict__ Xp, const unsigned short* __restrict__ Wb,
    const float* __restrict__ ps, const float* __restrict__ Wt,
    unsigned short* __restrict__ Xq, float* __restrict__ pool,
    float* __restrict__ outs) {
  constexpr int KS = K2 / 32;
  constexpr int NLD = 48 * (K2 / 8) / 256;  // uint4 per thread (3 or 6)
  constexpr int LDR = K2 + 8;   // halves; X-tile row stride
  constexpr int LDO = 132;      // floats; out-tile row stride
  __shared__ __align__(16) char smem[48 * LDO * 4];  // 25344 B, dual-purpose
  unsigned short* xt = (unsigned short*)smem;
  float* ot = (float*)smem;
  __shared__ float sb[768];
  __shared__ float spool[384];
  int tid = threadIdx.x;
  int bid = blockIdx.x;
  int b = bid >> 7;
  int nt = bid & 127;
  int p0 = nt * 48;

  int w = tid >> 6, lane = tid & 63;
  int q = lane >> 4, cl = lane & 15;

  // stage X tile [48][K2] -> LDS: issue ALL global loads first, then store
  {
    uint4 stg[NLD];
#pragma unroll
    for (int t = 0; t < NLD; ++t) {
      int ch = t * 256 + tid;
      int rp = ch / (K2 / 8), cc = ch % (K2 / 8);
      stg[t] = *(const uint4*)(Xp + ((size_t)b * P + p0 + rp) * K2 + cc * 8);
    }
#pragma unroll
    for (int t = 0; t < NLD; ++t) {
      int ch = t * 256 + tid;
      int rp = ch / (K2 / 8), cc = ch % (K2 / 8);
      *(uint4*)(xt + rp * LDR + cc * 8) = stg[t];
    }
  }
  if (HASPOOL) {
    // pooled mean (sum of 8 shadow copies) -> LDS
    for (int i = tid; i < 384; i += 256) {
      float x = 0.f;
#pragma unroll
      for (int k = 0; k < 8; ++k) x += ps[k * 3072 + b * 384 + i];
      spool[i] = x * (1.f / 2048.f);
    }
  }

  // first A-fragments: global, LDS-independent -> issue before the barrier
  bf16x8 acur[2][2], anxt[2][2];
#pragma unroll
  for (int t = 0; t < 2; ++t)
#pragma unroll
    for (int pd = 0; pd < 2; ++pd)
      acur[t][pd] = *(const bf16x8*)(Wb +
          (size_t)(32 * w + 16 * t + 128 * pd + cl) * 32 + q * 8);

  __syncthreads();
  if (HASPOOL) {
    // bias prologue: thread == stacked row m (0..127 = Wn, 128..255 = D)
    float s0 = 0.f, s1 = 0.f, s2 = 0.f;
#pragma unroll 16
    for (int c = 0; c < 128; ++c) {
      float x = Wt[c * 256 + tid];
      s0 = fmaf(x, spool[c * 3 + 0], s0);
      s1 = fmaf(x, spool[c * 3 + 1], s1);
      s2 = fmaf(x, spool[c * 3 + 2], s2);
    }
    sb[tid * 3 + 0] = s0;
    sb[tid * 3 + 1] = s1;
    sb[tid * 3 + 2] = s2;
    __syncthreads();
  }

  f32x4 acc[2][2][3] = {};  // [t][pd][v]

  bf16x8 bcur[3], bnxt[3];
#pragma unroll
  for (int v = 0; v < 3; ++v)
    bcur[v] = *(const bf16x8*)(xt + (v * 16 + cl) * LDR + q * 8);

#pragma unroll
  for (int ks = 0; ks < KS; ++ks) {
    if (ks + 1 < KS) {
#pragma unroll
      for (int t = 0; t < 2; ++t)
#pragma unroll
        for (int pd = 0; pd < 2; ++pd)
          anxt[t][pd] = *(const bf16x8*)(Wb +
              (size_t)(32 * w + 16 * t + 128 * pd + cl) * 32 + q * 8 +
              (ks + 1) * 8192);
#pragma unroll
      for (int v = 0; v < 3; ++v)
        bnxt[v] = *(const bf16x8*)(xt + (v * 16 + cl) * LDR + (ks + 1) * 32 + q * 8);
    }
#pragma unroll
    for (int t = 0; t < 2; ++t)
#pragma unroll
      for (int pd = 0; pd < 2; ++pd)
#pragma unroll
        for (int v = 0; v < 3; ++v)
          acc[t][pd][v] = __builtin_amdgcn_mfma_f32_16x16x32_bf16(
              acur[t][pd], bcur[v], acc[t][pd][v], 0, 0, 0);
#pragma unroll
    for (int t = 0; t < 2; ++t)
#pragma unroll
      for (int pd = 0; pd < 2; ++pd)
        acur[t][pd] = anxt[t][pd];
#pragma unroll
    for (int v = 0; v < 3; ++v) bcur[v] = bnxt[v];
  }
  __syncthreads();  // X-tile dead; buffer becomes the fp32 out-tile

#pragma unroll
  for (int t = 0; t < 2; ++t) {
    float res[3][4];
#pragma unroll
    for (int r = 0; r < 4; ++r) {
      int o = 32 * w + 16 * t + 4 * q + r;
      float pv[3], dvv[3];
#pragma unroll
      for (int v = 0; v < 3; ++v) {
        pv[v] = acc[t][0][v][r] + (HASPOOL ? sb[o * 3 + v] : 0.f);
        dvv[v] = acc[t][1][v][r] + (HASPOOL ? sb[(128 + o) * 3 + v] : 0.f);
      }
      float dot = fmaf(pv[0], dvv[0], fmaf(pv[1], dvv[1], pv[2] * dvv[2]));
      float dns = fmaf(dvv[0], dvv[0], fmaf(dvv[1], dvv[1], dvv[2] * dvv[2]));
      float f = (dot < 0.f) ? dot / (dns + 1e-6f) : 0.f;
#pragma unroll
      for (int v = 0; v < 3; ++v) res[v][r] = pv[v] - f * dvv[v];
    }
    int o0 = 32 * w + 16 * t + 4 * q;
#pragma unroll
    for (int v = 0; v < 3; ++v) {
      f32x4 rv = {res[v][0], res[v][1], res[v][2], res[v][3]};
      *(f32x4*)(ot + (v * 16 + cl) * LDO + o0) = rv;
    }
  }
  __syncthreads();

  // (a) coalesced pack + store of activated output FIRST (stores don't
  //     depend on the atomics; overlap the atomic latency tail)
  if (!LAST) {
    for (int s = tid; s < 1536; s += 256) {
      int pix = s >> 5, c4 = s & 31;
      const float* src = ot + pix * LDO + c4 * 4;
      uint4 vv;
      vv.x = packhl(src[0]);
      vv.y = packhl(src[1]);
      vv.z = packhl(src[2]);
      vv.w = packhl(src[3]);
      *(uint4*)(Xq + ((size_t)b * P + p0 + pix) * 256 + c4 * 8) = vv;
    }
  }

  // (b) pool sums: lane-dense atomics into shadow copy nt&7
  int shadow = (nt & 7) * 3072;
  for (int s = tid; s < 384; s += 256) {
    int o = s / 3, v = s % 3;
    float a2 = 0.f;
#pragma unroll
    for (int c = 0; c < 16; ++c) a2 += ot[(v * 16 + c) * LDO + o];
    if (LAST) atomicAdd(outs + shadow + b * 384 + s, a2);
    else      atomicAdd(pool + shadow + b * 384 + s, a2);
  }
}

// ---------------------------------------------------------------------------
// launch
// ---------------------------------------------------------------------------
extern "C" void kernel_launch(void* const* d_in, const int* in_sizes, int n_in,
                              void* d_out, int out_size, void* d_ws, size_t ws_size,
                              hipStream_t stream) {
  (void)in_sizes; (void)n_in; (void)out_size; (void)ws_size;
  const float* pc   = (const float*)d_in[0];
  const float* Wpos = (const float*)d_in[1];
  const float* Dpos = (const float*)d_in[2];
  const float* W1   = (const float*)d_in[3];
  const float* D1   = (const float*)d_in[4];
  const float* W2   = (const float*)d_in[5];
  const float* D2   = (const float*)d_in[6];
  const float* W3   = (const float*)d_in[7];
  const float* D3   = (const float*)d_in[8];
  float* out = (float*)d_out;
  float* ws  = (float*)d_ws;

  // fused prep + KNN + edge + pos layer -> Xp0 (+ packed weights, zeroed shadows)
  knn_edge_kernel<<<dim3(N / QPW, B), 512, 0, stream>>>(
      pc, Wpos, Dpos, W1, D1, W2, D2, W3, D3, ws);
  // layer1: K2=128 -> Xp1 + ps1 shadows
  gemm_vnt_kernel<128, false, false><<<1024, 256, 0, stream>>>(
      (const unsigned short*)(ws + OXP0), (const unsigned short*)(ws + OWB1),
      nullptr, nullptr, (unsigned short*)(ws + OXP1), ws + OPS1, nullptr);
  // layer2: bias prologue from ps1 + WT2 -> Xp2 + ps2 shadows
  gemm_vnt_kernel<256, true, false><<<1024, 256, 0, stream>>>(
      (const unsigned short*)(ws + OXP1), (const unsigned short*)(ws + OWB2),
      ws + OPS1, ws + OWT2, (unsigned short*)(ws + OXP2), ws + OPS2, nullptr);
  // layer3: bias prologue from ps2 + WT3 -> out shadows
  gemm_vnt_kernel<256, true, true><<<1024, 256, 0, stream>>>(
      (const unsigned short*)(ws + OXP2), (const unsigned short*)(ws + OWB3),
      ws + OPS2, ws + OWT3, nullptr, nullptr, ws + OOUTS);
  out_merge_kernel<<<12, 256, 0, stream>>>(ws + OOUTS, out);
}

// Round 19
// 168.130 us; speedup vs baseline: 1.0109x; 1.0109x over previous
//
#include <hip/hip_runtime.h>
#include <hip/hip_bf16.h>
#include <math.h>

// ---------------------------------------------------------------------------
// Problem constants
// ---------------------------------------------------------------------------
constexpr int B = 8;
constexpr int N = 2048;
constexpr int KNN = 20;
constexpr int H = 128;
constexpr int P = 3 * N;  // 6144 pixels per batch
constexpr int QPW = 8;    // queries (waves) per knn_edge block

// ws layout (float offsets)
constexpr int OWT2   = 8448;      // W2/D2 second-half TRANSPOSED [c<128][m<256] (32768)
constexpr int OWT3   = 41216;     // W3/D3 second-half transposed (32768)
constexpr int OPS1   = 73984;     // poolsum1 shadows [8][B][128][3] = 24576
constexpr int OPS2   = 98560;     // poolsum2 shadows = 24576
constexpr int OOUTS  = 123136;    // out shadows [8][B][384] = 24576
constexpr int OWB1   = 160000;    // Wbig1 bf16 hi/lo, FRAGMENT-MAJOR [ks][256][32h] (16384 f)
constexpr int OWB2   = 176384;    // Wbig2 fragment-major (32768 f)
constexpr int OWB3   = 209152;    // Wbig3 fragment-major (32768 f)
constexpr int OXP0   = 569600;    // Xp0 bf16 [b][P][128] (3145728 f-equiv)
constexpr int OXP2   = 569600;    // Xp2 bf16 [b][P][256] reuses Xp0 region
constexpr int OXP1   = 6861056;   // Xp1 bf16 [b][P][256] (6291456 f-equiv)
// max extent 13,152,512 floats ~= 52.6 MB

constexpr int ZERO_BASE = OPS1;   // zeroed region = ps1+ps2+outs
constexpr int ZERO_CNT  = 73728;

typedef __attribute__((ext_vector_type(8))) short bf16x8;
typedef __attribute__((ext_vector_type(4))) float f32x4;

__device__ __forceinline__ unsigned short f2bf(float x) {
  __hip_bfloat16 h = __float2bfloat16(x);
  return *(unsigned short*)&h;
}
__device__ __forceinline__ float bf2f(unsigned short u) {
  __hip_bfloat16 h;
  *(unsigned short*)&h = u;
  return __bfloat162float(h);
}
// pack x as (hi, lo) bf16 pair in one uint (hi at lower address)
__device__ __forceinline__ unsigned int packhl(float x) {
  unsigned short hi = f2bf(x);
  float lo = x - bf2f(hi);
  unsigned short ls = f2bf(lo);
  return (unsigned)hi | ((unsigned)ls << 16);
}

// ---------------------------------------------------------------------------
// Wave-wide bitonic sort of 64 u64 keys, descending (larger key = better).
// Key = ord(value)<<32 | ~index  ==>  value desc, ties -> smaller index.
// ---------------------------------------------------------------------------
__device__ __forceinline__ void wave_sort_key(unsigned long long& k, int lane) {
#pragma unroll
  for (int kk = 2; kk <= 64; kk <<= 1) {
#pragma unroll
    for (int j = kk >> 1; j > 0; j >>= 1) {
      unsigned long long pk =
          (unsigned long long)__shfl_xor((long long)k, j);
      bool iam_lower   = (lane & j) == 0;
      bool dir_desc    = (lane & kk) == 0;
      bool p_better    = pk > k;
      bool want_better = (dir_desc == iam_lower);
      k = (p_better == want_better) ? pk : k;
    }
  }
}

// ---------------------------------------------------------------------------
// K2 (FUSED): prep + exact top-20 KNN + edge + pos layer + mean-k -> Xp0.
// ---------------------------------------------------------------------------
__global__ __launch_bounds__(512, 8) void knn_edge_kernel(
    const float* __restrict__ pc, const float* __restrict__ Wpos,
    const float* __restrict__ Dp,
    const float* __restrict__ W1, const float* __restrict__ D1,
    const float* __restrict__ W2, const float* __restrict__ D2,
    const float* __restrict__ W3, const float* __restrict__ D3,
    float* __restrict__ ws) {
  __shared__ float4 spt[N];                       // 32 KB (2x,2y,2z,xx)
  __shared__ __align__(16) unsigned char sphase[QPW][640];   // 5 KB
  int tid = threadIdx.x;
  int b = blockIdx.y;
  int bid = blockIdx.y * gridDim.x + blockIdx.x;  // 0..2047
  int wv = tid >> 6, lane = tid & 63;
  unsigned short* Xp0 = (unsigned short*)(ws + OXP0);
  unsigned short* sbufw = (unsigned short*)sphase[wv];
  float4* erw = (float4*)sphase[wv];

  // hoisted edge-phase weight loads (latency hidden under distance pass)
  int o = lane;
  float w0 = Wpos[o * 3 + 0], w1 = Wpos[o * 3 + 1], w2 = Wpos[o * 3 + 2];
  float e0 = Dp[o * 3 + 0], e1 = Dp[o * 3 + 1], e2 = Dp[o * 3 + 2];

  // ---- folded prep: distributed shadow zeroing (1 store/thread) ----------
  {
    int zi = bid * 512 + tid;
    if (zi < ZERO_CNT) ws[ZERO_BASE + zi] = 0.f;
  }
  // ---- folded prep: 768 weight rows over blocks 0..95 (one wave/row) -----
  if (bid < 96) {
    int rr = bid * 8 + wv;  // 0..767
    const float* src;
    float* tdst = nullptr;
    unsigned int* pdst;   // base of fragment-major region + m*16
    int C, Cpack;
    bool norm;
    if (rr < 128)      { src = W1 + rr * 64;            C = 64;  Cpack = 64;  norm = true;
                         pdst = (unsigned int*)(ws + OWB1) + rr * 16; }
    else if (rr < 256) { int m = rr - 128; src = D1 + m * 64;  C = 64;  Cpack = 64;  norm = false;
                         pdst = (unsigned int*)(ws + OWB1) + (m + 128) * 16; }
    else if (rr < 384) { int m = rr - 256; src = W2 + m * 256; C = 256; Cpack = 128; norm = true;
                         pdst = (unsigned int*)(ws + OWB2) + m * 16; tdst = ws + OWT2 + m; }
    else if (rr < 512) { int m = rr - 384; src = D2 + m * 256; C = 256; Cpack = 128; norm = false;
                         pdst = (unsigned int*)(ws + OWB2) + (m + 128) * 16; tdst = ws + OWT2 + 128 + m; }
    else if (rr < 640) { int m = rr - 512; src = W3 + m * 256; C = 256; Cpack = 128; norm = true;
                         pdst = (unsigned int*)(ws + OWB3) + m * 16; tdst = ws + OWT3 + m; }
    else               { int m = rr - 640; src = D3 + m * 256; C = 256; Cpack = 128; norm = false;
                         pdst = (unsigned int*)(ws + OWB3) + (m + 128) * 16; tdst = ws + OWT3 + 128 + m; }
    float s = 1.f;
    if (norm) {
      float a = 0.f;
      for (int i = lane; i < C; i += 64) a += src[i];
#pragma unroll
      for (int off = 32; off > 0; off >>= 1) a += __shfl_xor(a, off);
      s = a;
    }
    for (int i = lane; i < C; i += 64) {
      float val = src[i] / s;  // exact when s==1
      if (i < Cpack) pdst[(i >> 4) * 4096 + (i & 15)] = packhl(val);
      if (tdst && i >= 128) tdst[(i - 128) * 256] = val;
    }
  }

  // ---- stage point cloud ---------------------------------------------------
  const float* pcb = pc + (size_t)b * N * 3;
  for (int i = tid; i < N; i += 512) {
    float x = pcb[i * 3 + 0], y = pcb[i * 3 + 1], z = pcb[i * 3 + 2];
    float xx = __fadd_rn(__fadd_rn(__fmul_rn(x, x), __fmul_rn(y, y)), __fmul_rn(z, z));
    spt[i] = make_float4(2.f * x, 2.f * y, 2.f * z, xx);
  }
  __syncthreads();
  int q = blockIdx.x * QPW + wv;
  float4 qp = spt[q];
  float qx = 0.5f * qp.x, qy = 0.5f * qp.y, qz = 0.5f * qp.z, qxx = qp.w;

  float dv[32];
  float lmax = -INFINITY;
#pragma unroll
  for (int i = 0; i < 32; ++i) {
    float4 m = spt[i * 64 + lane];
    float A = __fadd_rn(__fadd_rn(__fmul_rn(m.x, qx), __fmul_rn(m.y, qy)),
                        __fmul_rn(m.z, qz));
    float d = __fsub_rn(__fsub_rn(A, qxx), m.w);
    dv[i] = d;
    lmax = fmaxf(lmax, d);
  }

  // value-only bitonic sort (descending) of the 64 lane-maxes; take #19
  float sv = lmax;
#pragma unroll
  for (int k = 2; k <= 64; k <<= 1) {
#pragma unroll
    for (int j = k >> 1; j > 0; j >>= 1) {
      float pv = __shfl_xor(sv, j);
      bool keep_max = ((lane & k) == 0) == ((lane & j) == 0);
      sv = keep_max ? fmaxf(sv, pv) : fminf(sv, pv);
    }
  }
  float tval = __shfl(sv, 19);  // 20th-largest lane-max <= V20 (provable)

  // registerized compact: per-lane survivor mask + shfl prefix scan
  unsigned msk = 0u;
#pragma unroll
  for (int i = 0; i < 32; ++i) msk |= (dv[i] >= tval) ? (1u << i) : 0u;
  int cnt = __popc(msk);
  int scan = cnt;
#pragma unroll
  for (int off = 1; off < 64; off <<= 1) {
    int t = __shfl_up(scan, off);
    scan += (lane >= off) ? t : 0;
  }
  int S = __shfl(scan, 63);
  int pos = scan - cnt;  // exclusive prefix
  unsigned mm = msk;
  while (mm) {
    int i = __ffs(mm) - 1;
    mm &= mm - 1;
    if (pos < 192) sbufw[pos] = (unsigned short)(i * 64 + lane);
    ++pos;
  }

  auto distOf = [&](int m) -> float {
    float4 mp = spt[m];
    float A = __fadd_rn(__fadd_rn(__fmul_rn(mp.x, qx), __fmul_rn(mp.y, qy)),
                        __fmul_rn(mp.z, qz));
    return __fsub_rn(__fsub_rn(A, qxx), mp.w);
  };
  auto mkkey = [&](int m) -> unsigned long long {
    float d = distOf(m);
    unsigned u = __float_as_uint(d);
    u ^= (u >> 31) ? 0xFFFFFFFFu : 0x80000000u;
    return ((unsigned long long)u << 32) | (unsigned)(~m);
  };

  unsigned long long key = 0ULL;  // padding key: below every real key
  if (S <= 64) {
    if (lane < S) key = mkkey(sbufw[lane]);
    wave_sort_key(key, lane);
  } else if (S <= 192) {
    int p2 = 0;
    while (p2 < S) {
      if (lane >= KNN) {
        int t = p2 + lane - KNN;
        key = (t < S) ? mkkey(sbufw[t]) : 0ULL;
      }
      wave_sort_key(key, lane);
      p2 += 64 - KNN;
    }
  } else {
    int p2 = 0;
    while (p2 < N) {
      if (lane >= KNN) {
        int t = p2 + lane - KNN;
        key = (t < N) ? mkkey(t) : 0ULL;
      }
      wave_sort_key(key, lane);
      p2 += 64 - KNN;
    }
  }
  int cm = ~((unsigned)key);  // valid in lanes 0..19

  // ---- edge geometry precompute: lane k<20 computes e/r once --------------
  if (lane < KNN) {
    float4 t = spt[cm];
    float nx = 0.5f * t.x, ny = 0.5f * t.y, nz = 0.5f * t.z;
    float ex = nx - qx, ey = ny - qy, ez = nz - qz;
    float rx = ny * qz - nz * qy;
    float ry = nz * qx - nx * qz;
    float rz = nx * qy - ny * qx;
    erw[2 * lane + 0] = make_float4(ex, ey, ez, 0.f);
    erw[2 * lane + 1] = make_float4(rx, ry, rz, 0.f);
  }

  // ---- edge + pos layer (lane o = channel o) -------------------------------
  {
    float s = (w0 + w2) + w1;
    w0 = w0 / s; w1 = w1 / s; w2 = w2 / s;
  }
  float cx = qx, cy = qy, cz = qz;  // exact raw coords (0.5 * 2x)
  float pcx = w1 * cx, pcy = w1 * cy, pcz = w1 * cz;
  float dcx = e1 * cx, dcy = e1 * cy, dcz = e1 * cz;
  float ax = 0.f, ay = 0.f, az = 0.f;
#pragma unroll 4
  for (int k = 0; k < KNN; ++k) {
    float4 e4 = erw[2 * k + 0];   // broadcast LDS reads
    float4 r4 = erw[2 * k + 1];
    float ex = e4.x, ey = e4.y, ez = e4.z;
    float rx = r4.x, ry = r4.y, rz = r4.z;
    float px = fmaf(w0, ex, fmaf(w2, rx, pcx));
    float py = fmaf(w0, ey, fmaf(w2, ry, pcy));
    float pz = fmaf(w0, ez, fmaf(w2, rz, pcz));
    float dx = fmaf(e0, ex, fmaf(e2, rx, dcx));
    float dy = fmaf(e0, ey, fmaf(e2, ry, dcy));
    float dz = fmaf(e0, ez, fmaf(e2, rz, dcz));
    float dot = fmaf(px, dx, fmaf(py, dy, pz * dz));
    float dns = fmaf(dx, dx, fmaf(dy, dy, dz * dz)) + 1e-6f;
    float r0 = __builtin_amdgcn_rcpf(dns);
    r0 = r0 * fmaf(-dns, r0, 2.0f);          // 1 Newton step
    float f = (dot < 0.f) ? dot * r0 : 0.f;
    ax = fmaf(-f, dx, px) + ax;
    ay = fmaf(-f, dy, py) + ay;
    az = fmaf(-f, dz, pz) + az;
  }
  int pbase = ((q >> 4) * 48) + (q & 15);
  unsigned short* dst = Xp0 + ((size_t)b * P + pbase) * 128 + 2 * o;
  *(unsigned int*)(dst)              = packhl(ax * (1.f / 20.f));
  *(unsigned int*)(dst + 16 * 128)   = packhl(ay * (1.f / 20.f));
  *(unsigned int*)(dst + 32 * 128)   = packhl(az * (1.f / 20.f));
}

// ---------------------------------------------------------------------------
// K9: merge 8 out shadows -> d_out (mean over N).
// ---------------------------------------------------------------------------
__global__ __launch_bounds__(256) void out_merge_kernel(
    const float* __restrict__ outs, float* __restrict__ out) {
  int idx = blockIdx.x * 256 + threadIdx.x;  // 3072
  if (idx >= B * 384) return;
  float s = 0.f;
#pragma unroll
  for (int k = 0; k < 8; ++k) s += outs[k * 3072 + idx];
  out[idx] = s * (1.f / 2048.f);
}

// ---------------------------------------------------------------------------
// K4/K6/K8: MFMA VNT layer (round-17 measured-best config: acur hoisted
// before the staging barrier, bias prologue at unroll 16, sequential staging,
// A-only K-loop prefetch, atomics-then-stores epilogue).
// ---------------------------------------------------------------------------
template <int K2, bool HASPOOL, bool LAST>
__global__ __launch_bounds__(256, 4) void gemm_vnt_kernel(
    const unsigned short* __restrict__ Xp, const unsigned short* __restrict__ Wb,
    const float* __restrict__ ps, const float* __restrict__ Wt,
    unsigned short* __restrict__ Xq, float* __restrict__ pool,
    float* __restrict__ outs) {
  constexpr int KS = K2 / 32;
  constexpr int LDR = K2 + 8;   // halves; X-tile row stride
  constexpr int LDO = 132;      // floats; out-tile row stride
  __shared__ __align__(16) char smem[48 * LDO * 4];  // 25344 B, dual-purpose
  unsigned short* xt = (unsigned short*)smem;
  float* ot = (float*)smem;
  __shared__ float sb[768];
  __shared__ float spool[384];
  int tid = threadIdx.x;
  int bid = blockIdx.x;
  int b = bid >> 7;
  int nt = bid & 127;
  int p0 = nt * 48;

  int w = tid >> 6, lane = tid & 63;
  int q = lane >> 4, cl = lane & 15;

  // stage X tile [48][K2] -> LDS
  for (int ch = tid; ch < 48 * (K2 / 8); ch += 256) {
    int rp = ch / (K2 / 8), cc = ch % (K2 / 8);
    *(uint4*)(xt + rp * LDR + cc * 8) =
        *(const uint4*)(Xp + ((size_t)b * P + p0 + rp) * K2 + cc * 8);
  }
  if (HASPOOL) {
    // pooled mean (sum of 8 shadow copies) -> LDS
    for (int i = tid; i < 384; i += 256) {
      float x = 0.f;
#pragma unroll
      for (int k = 0; k < 8; ++k) x += ps[k * 3072 + b * 384 + i];
      spool[i] = x * (1.f / 2048.f);
    }
  }

  // first A-fragments: global, LDS-independent -> issue before the barrier
  bf16x8 acur[2][2], anxt[2][2];
#pragma unroll
  for (int t = 0; t < 2; ++t)
#pragma unroll
    for (int pd = 0; pd < 2; ++pd)
      acur[t][pd] = *(const bf16x8*)(Wb +
          (size_t)(32 * w + 16 * t + 128 * pd + cl) * 32 + q * 8);

  __syncthreads();
  if (HASPOOL) {
    // bias prologue: thread == stacked row m (0..127 = Wn, 128..255 = D)
    float s0 = 0.f, s1 = 0.f, s2 = 0.f;
#pragma unroll 16
    for (int c = 0; c < 128; ++c) {
      float x = Wt[c * 256 + tid];
      s0 = fmaf(x, spool[c * 3 + 0], s0);
      s1 = fmaf(x, spool[c * 3 + 1], s1);
      s2 = fmaf(x, spool[c * 3 + 2], s2);
    }
    sb[tid * 3 + 0] = s0;
    sb[tid * 3 + 1] = s1;
    sb[tid * 3 + 2] = s2;
    __syncthreads();
  }

  f32x4 acc[2][2][3] = {};  // [t][pd][v]

#pragma unroll
  for (int ks = 0; ks < KS; ++ks) {
    if (ks + 1 < KS) {
#pragma unroll
      for (int t = 0; t < 2; ++t)
#pragma unroll
        for (int pd = 0; pd < 2; ++pd)
          anxt[t][pd] = *(const bf16x8*)(Wb +
              (size_t)(32 * w + 16 * t + 128 * pd + cl) * 32 + q * 8 +
              (ks + 1) * 8192);
    }
    bf16x8 bb[3];
#pragma unroll
    for (int v = 0; v < 3; ++v)
      bb[v] = *(const bf16x8*)(xt + (v * 16 + cl) * LDR + ks * 32 + q * 8);
#pragma unroll
    for (int t = 0; t < 2; ++t)
#pragma unroll
      for (int pd = 0; pd < 2; ++pd)
#pragma unroll
        for (int v = 0; v < 3; ++v)
          acc[t][pd][v] = __builtin_amdgcn_mfma_f32_16x16x32_bf16(
              acur[t][pd], bb[v], acc[t][pd][v], 0, 0, 0);
#pragma unroll
    for (int t = 0; t < 2; ++t)
#pragma unroll
      for (int pd = 0; pd < 2; ++pd)
        acur[t][pd] = anxt[t][pd];
  }
  __syncthreads();  // X-tile dead; buffer becomes the fp32 out-tile

#pragma unroll
  for (int t = 0; t < 2; ++t) {
    float res[3][4];
#pragma unroll
    for (int r = 0; r < 4; ++r) {
      int o = 32 * w + 16 * t + 4 * q + r;
      float pv[3], dvv[3];
#pragma unroll
      for (int v = 0; v < 3; ++v) {
        pv[v] = acc[t][0][v][r] + (HASPOOL ? sb[o * 3 + v] : 0.f);
        dvv[v] = acc[t][1][v][r] + (HASPOOL ? sb[(128 + o) * 3 + v] : 0.f);
      }
      float dot = fmaf(pv[0], dvv[0], fmaf(pv[1], dvv[1], pv[2] * dvv[2]));
      float dns = fmaf(dvv[0], dvv[0], fmaf(dvv[1], dvv[1], dvv[2] * dvv[2]));
      float f = (dot < 0.f) ? dot / (dns + 1e-6f) : 0.f;
#pragma unroll
      for (int v = 0; v < 3; ++v) res[v][r] = pv[v] - f * dvv[v];
    }
    int o0 = 32 * w + 16 * t + 4 * q;
#pragma unroll
    for (int v = 0; v < 3; ++v) {
      f32x4 rv = {res[v][0], res[v][1], res[v][2], res[v][3]};
      *(f32x4*)(ot + (v * 16 + cl) * LDO + o0) = rv;
    }
  }
  __syncthreads();

  int shadow = (nt & 7) * 3072;
  for (int s = tid; s < 384; s += 256) {
    int o = s / 3, v = s % 3;
    float a2 = 0.f;
#pragma unroll
    for (int c = 0; c < 16; ++c) a2 += ot[(v * 16 + c) * LDO + o];
    if (LAST) atomicAdd(outs + shadow + b * 384 + s, a2);
    else      atomicAdd(pool + shadow + b * 384 + s, a2);
  }

  if (!LAST) {
    for (int s = tid; s < 1536; s += 256) {
      int pix = s >> 5, c4 = s & 31;
      const float* src = ot + pix * LDO + c4 * 4;
      uint4 vv;
      vv.x = packhl(src[0]);
      vv.y = packhl(src[1]);
      vv.z = packhl(src[2]);
      vv.w = packhl(src[3]);
      *(uint4*)(Xq + ((size_t)b * P + p0 + pix) * 256 + c4 * 8) = vv;
    }
  }
}

// ---------------------------------------------------------------------------
// launch
// ---------------------------------------------------------------------------
extern "C" void kernel_launch(void* const* d_in, const int* in_sizes, int n_in,
                              void* d_out, int out_size, void* d_ws, size_t ws_size,
                              hipStream_t stream) {
  (void)in_sizes; (void)n_in; (void)out_size; (void)ws_size;
  const float* pc   = (const float*)d_in[0];
  const float* Wpos = (const float*)d_in[1];
  const float* Dpos = (const float*)d_in[2];
  const float* W1   = (const float*)d_in[3];
  const float* D1   = (const float*)d_in[4];
  const float* W2   = (const float*)d_in[5];
  const float* D2   = (const float*)d_in[6];
  const float* W3   = (const float*)d_in[7];
  const float* D3   = (const float*)d_in[8];
  float* out = (float*)d_out;
  float* ws  = (float*)d_ws;

  // fused prep + KNN + edge + pos layer -> Xp0 (+ packed weights, zeroed shadows)
  knn_edge_kernel<<<dim3(N / QPW, B), 512, 0, stream>>>(
      pc, Wpos, Dpos, W1, D1, W2, D2, W3, D3, ws);
  // layer1: K2=128 -> Xp1 + ps1 shadows
  gemm_vnt_kernel<128, false, false><<<1024, 256, 0, stream>>>(
      (const unsigned short*)(ws + OXP0), (const unsigned short*)(ws + OWB1),
      nullptr, nullptr, (unsigned short*)(ws + OXP1), ws + OPS1, nullptr);
  // layer2: bias prologue from ps1 + WT2 -> Xp2 + ps2 shadows
  gemm_vnt_kernel<256, true, false><<<1024, 256, 0, stream>>>(
      (const unsigned short*)(ws + OXP1), (const unsigned short*)(ws + OWB2),
      ws + OPS1, ws + OWT2, (unsigned short*)(ws + OXP2), ws + OPS2, nullptr);
  // layer3: bias prologue from ps2 + WT3 -> out shadows
  gemm_vnt_kernel<256, true, true><<<1024, 256, 0, stream>>>(
      (const unsigned short*)(ws + OXP2), (const unsigned short*)(ws + OWB3),
      ws + OPS2, ws + OWT3, nullptr, nullptr, ws + OOUTS);
  out_merge_kernel<<<12, 256, 0, stream>>>(ws + OOUTS, out);
}